// Round 9
// baseline (517.227 us; speedup 1.0000x reference)
//
#include <hip/hip_runtime.h>
#include <math.h>

#define B_ 32
#define T_ 1024
#define C_ 768
#define M_ (B_ * T_)   // 32768

typedef __attribute__((ext_vector_type(8))) short bf16x8;
typedef __attribute__((ext_vector_type(4))) float f32x4;
typedef __attribute__((ext_vector_type(8))) unsigned short u16x8;
typedef __attribute__((address_space(1))) const void g_void;
typedef __attribute__((address_space(3))) void lds_void;

__device__ __forceinline__ unsigned short f2bf(float f) {
  union { float f; unsigned int u; } v; v.f = f;
  unsigned int u = v.u;
  u += 0x7fffu + ((u >> 16) & 1u);   // RNE
  return (unsigned short)(u >> 16);
}
__device__ __forceinline__ float b2f(unsigned short h) {
  union { unsigned int u; float f; } v; v.u = ((unsigned int)h) << 16;
  return v.f;
}
__device__ __forceinline__ float blo(unsigned int p) {
  union { unsigned int u; float f; } v; v.u = p << 16;
  return v.f;
}
__device__ __forceinline__ float bhi(unsigned int p) {
  union { unsigned int u; float f; } v; v.u = p & 0xffff0000u;
  return v.f;
}

// ---------------------------------------------------------------------------
// Fused time-shift mix: read x once, emit xk, xv, xr (bf16)
// ---------------------------------------------------------------------------
__global__ __launch_bounds__(256) void mix3_bf16(const float* __restrict__ x,
                                                 const float* __restrict__ tmk,
                                                 const float* __restrict__ tmv,
                                                 const float* __restrict__ tmr,
                                                 unsigned short* __restrict__ ok,
                                                 unsigned short* __restrict__ ov,
                                                 unsigned short* __restrict__ orr) {
  const unsigned int gi = blockIdx.x * 256u + threadIdx.x;  // group of 8 elems
  const int m = gi / (C_ / 8);
  const int c8 = (gi % (C_ / 8)) * 8;
  const float* xp = x + (size_t)m * C_ + c8;
  float xv8[8], xx8[8], t8[8];
  *(float4*)&xv8[0] = *(const float4*)xp;
  *(float4*)&xv8[4] = *(const float4*)(xp + 4);
  if ((m & (T_ - 1)) != 0) {
    *(float4*)&xx8[0] = *(const float4*)(xp - C_);
    *(float4*)&xx8[4] = *(const float4*)(xp - C_ + 4);
  } else {
#pragma unroll
    for (int i = 0; i < 8; ++i) xx8[i] = 0.f;
  }
  const size_t ob = (size_t)m * C_ + c8;

  *(float4*)&t8[0] = *(const float4*)(tmk + c8);
  *(float4*)&t8[4] = *(const float4*)(tmk + c8 + 4);
  u16x8 o;
#pragma unroll
  for (int i = 0; i < 8; ++i) o[i] = f2bf(xv8[i] * t8[i] + xx8[i] * (1.f - t8[i]));
  *(u16x8*)(ok + ob) = o;

  *(float4*)&t8[0] = *(const float4*)(tmv + c8);
  *(float4*)&t8[4] = *(const float4*)(tmv + c8 + 4);
#pragma unroll
  for (int i = 0; i < 8; ++i) o[i] = f2bf(xv8[i] * t8[i] + xx8[i] * (1.f - t8[i]));
  *(u16x8*)(ov + ob) = o;

  *(float4*)&t8[0] = *(const float4*)(tmr + c8);
  *(float4*)&t8[4] = *(const float4*)(tmr + c8 + 4);
#pragma unroll
  for (int i = 0; i < 8; ++i) o[i] = f2bf(xv8[i] * t8[i] + xx8[i] * (1.f - t8[i]));
  *(u16x8*)(orr + ob) = o;
}

// f32 -> bf16 for all 4 weight matrices in one launch (blockIdx.y selects)
__global__ __launch_bounds__(256) void cvt4_bf16(const float* __restrict__ s0,
                                                 const float* __restrict__ s1,
                                                 const float* __restrict__ s2,
                                                 const float* __restrict__ s3,
                                                 unsigned short* __restrict__ d0,
                                                 unsigned short* __restrict__ d1,
                                                 unsigned short* __restrict__ d2,
                                                 unsigned short* __restrict__ d3) {
  const float* src = (blockIdx.y == 0) ? s0 : (blockIdx.y == 1) ? s1
                     : (blockIdx.y == 2) ? s2 : s3;
  unsigned short* dst = (blockIdx.y == 0) ? d0 : (blockIdx.y == 1) ? d1
                        : (blockIdx.y == 2) ? d2 : d3;
  const int gi = blockIdx.x * 256 + threadIdx.x;
  const float* p = src + (size_t)gi * 8;
  float v[8];
  *(float4*)&v[0] = *(const float4*)p;
  *(float4*)&v[4] = *(const float4*)(p + 4);
  u16x8 o;
#pragma unroll
  for (int i = 0; i < 8; ++i) o[i] = f2bf(v[i]);
  *(u16x8*)(dst + (size_t)gi * 8) = o;
}

// ---------------------------------------------------------------------------
// Pipelined bf16 GEMM: out[m][n] = sum_k A[m][k] * W[n][k]
// BM=256 x BN=128 tile, BK=64, 8 waves (2M x 4N), wave tile 128x32.
// Triple-buffered LDS K-tiles (144 KiB, 1 block/CU), depth-3 prefetch,
// counted vmcnt (12 -> 6 -> 0), raw s_barrier, T2 XOR swizzle both sides,
// T5 setprio around MFMA cluster.  (round-7 proven)
// ---------------------------------------------------------------------------
#define GBM 256
#define GBN 128
#define GBK 64
#define GNB ((M_ / GBM) * (C_ / GBN))  // 128*6 = 768
#define NT (C_ / GBK)                  // 12 K-tiles
#define BUFSZ 24576                    // shorts per buffer (A 16384 + B 8192)
#define BOFF_B 16384

#define WAITV(n) asm volatile("s_waitcnt vmcnt(" #n ")" ::: "memory")

template <int OUT_BF16>
__global__ __launch_bounds__(512) void gemm8(const unsigned short* __restrict__ A,
                                             const unsigned short* __restrict__ W,
                                             void* __restrict__ outv) {
  __shared__ unsigned short lds[3 * BUFSZ];   // 147456 B

  int bid = (int)blockIdx.x;
  bid = (bid & 7) * (GNB / 8) + (bid >> 3);   // bijective: 768 % 8 == 0
  const int mt = bid / (C_ / GBN);
  const int nt = bid % (C_ / GBN);
  const int m0 = mt * GBM, n0 = nt * GBN;

  const int tid = threadIdx.x;
  const int lane = tid & 63;
  const int wv = tid >> 6;        // 0..7
  const int wm = wv >> 2;         // 0..1
  const int wn = wv & 3;          // 0..3

  // staging: pre-swizzled global source, linear LDS dest (rule #21)
  const int l3 = lane >> 3;
  const int scol = (((lane & 7) ^ l3) << 3);   // element offset of 16B chunk
  const unsigned short* abase = A + (size_t)(m0 + wv * 8 + l3) * C_ + scol;
  const unsigned short* wbase = W + (size_t)(n0 + wv * 8 + l3) * C_ + scol;

#define STAGE(tt, bi)                                                         \
  {                                                                           \
    const int kk0_ = (tt) * GBK;                                              \
    _Pragma("unroll") for (int s_ = 0; s_ < 4; ++s_)                          \
        __builtin_amdgcn_global_load_lds(                                     \
            (g_void*)(abase + (size_t)s_ * 64 * C_ + kk0_),                   \
            (lds_void*)&lds[(bi) * BUFSZ + s_ * 4096 + wv * 512], 16, 0, 0);  \
    _Pragma("unroll") for (int s_ = 0; s_ < 2; ++s_)                          \
        __builtin_amdgcn_global_load_lds(                                     \
            (g_void*)(wbase + (size_t)s_ * 64 * C_ + kk0_),                   \
            (lds_void*)&lds[(bi) * BUFSZ + BOFF_B + s_ * 4096 + wv * 512],    \
            16, 0, 0);                                                        \
  }

  STAGE(0, 0);
  STAGE(1, 1);
  STAGE(2, 2);

  f32x4 acc[8][2] = {};
  const int arow = wm * 128 + (lane & 15);
  const int brow = wn * 32 + (lane & 15);

  int bufc = 0;
  for (int t = 0; t < NT; ++t) {
    if (t < NT - 2) { WAITV(12); }
    else if (t == NT - 2) { WAITV(6); }
    else { WAITV(0); }
    __builtin_amdgcn_s_barrier();
    __builtin_amdgcn_sched_barrier(0);

    const unsigned short* bufA = &lds[bufc * BUFSZ];
    const unsigned short* bufB = bufA + BOFF_B;

#pragma unroll
    for (int kk = 0; kk < 2; ++kk) {
      const int sw = ((((kk << 2) | (lane >> 4)) ^ (lane & 7)) << 3);
      bf16x8 af[8], bfv[2];
#pragma unroll
      for (int f = 0; f < 8; ++f)
        af[f] = *(const bf16x8*)&bufA[(arow + f * 16) * 64 + sw];
#pragma unroll
      for (int f = 0; f < 2; ++f)
        bfv[f] = *(const bf16x8*)&bufB[(brow + f * 16) * 64 + sw];
      __builtin_amdgcn_s_setprio(1);
#pragma unroll
      for (int i = 0; i < 8; ++i)
#pragma unroll
        for (int j = 0; j < 2; ++j)
          acc[i][j] = __builtin_amdgcn_mfma_f32_16x16x32_bf16(af[i], bfv[j], acc[i][j], 0, 0, 0);
      __builtin_amdgcn_s_setprio(0);
    }

    __builtin_amdgcn_s_barrier();
    __builtin_amdgcn_sched_barrier(0);
    if (t + 3 < NT) STAGE(t + 3, bufc);
    bufc = (bufc == 2) ? 0 : bufc + 1;
  }

  const int crow0 = m0 + wm * 128 + (lane >> 4) * 4;
  const int ccol0 = n0 + wn * 32 + (lane & 15);
  if (OUT_BF16) {
    unsigned short* out = (unsigned short*)outv;
#pragma unroll
    for (int i = 0; i < 8; ++i)
#pragma unroll
      for (int j = 0; j < 2; ++j)
#pragma unroll
        for (int r = 0; r < 4; ++r)
          out[(size_t)(crow0 + i * 16 + r) * C_ + ccol0 + j * 16] = f2bf(acc[i][j][r]);
  } else {
    float* out = (float*)outv;
#pragma unroll
    for (int i = 0; i < 8; ++i)
#pragma unroll
      for (int j = 0; j < 2; ++j)
#pragma unroll
        for (int r = 0; r < 4; ++r)
          out[(size_t)(crow0 + i * 16 + r) * C_ + ccol0 + j * 16] = acc[i][j][r];
  }
#undef STAGE
}

// ---------------------------------------------------------------------------
// WKV chunked associative scan. NCH=16 chunks of CL=64; k,v cached in 64
// packed VGPRs across both passes. 512-thread block, plain
// __launch_bounds__(512):
//  - r5: (512,4) -> 64-VGPR cap -> spill (arg acts as min-BLOCKS/CU here)
//  - r7: 1024, no arg -> 64-VGPR cap -> spill
//  - r8: (1024,1) -> STILL 64 (hint ignored for flat-1024 workgroups)
//  - gemm8: 512, no arg -> >64 VGPRs granted, no scratch  <- follow this
// ---------------------------------------------------------------------------
#define NCH 16
#define CL  (T_ / NCH)   // 64
#define CGRP 32

__global__ __launch_bounds__(512) void wkv_scan(const unsigned short* __restrict__ kin,
                                                const unsigned short* __restrict__ vin,
                                                const unsigned short* __restrict__ rin,
                                                const float* __restrict__ wdec,
                                                const float* __restrict__ ufirst,
                                                unsigned short* __restrict__ z) {
  __shared__ float ps[NCH][CGRP], qs[NCH][CGRP], os[NCH][CGRP];

  const int b = blockIdx.x / (C_ / CGRP);
  const int cg = blockIdx.x % (C_ / CGRP);
  const int ci = threadIdx.x & (CGRP - 1);
  const int j = threadIdx.x >> 5;            // chunk 0..15
  const int c = cg * CGRP + ci;
  const float w = wdec[c], u = ufirst[c];
  const size_t base = ((size_t)b * T_ + (size_t)j * CL) * C_ + c;

  // ---- phase 0: load k,v once, packed 2 bf16 per VGPR (64 VGPRs) ----
  unsigned int kp[CL / 2], vp[CL / 2];
#pragma unroll
  for (int i = 0; i < CL / 2; ++i) {
    const size_t i0 = base + (size_t)(2 * i) * C_;
    const unsigned int k0 = kin[i0], k1 = kin[i0 + C_];
    const unsigned int v0 = vin[i0], v1 = vin[i0 + C_];
    kp[i] = k0 | (k1 << 16);
    vp[i] = v0 | (v1 << 16);
  }

  // ---- phase 1: local chunk scan from registers ----
  float p = 0.f, q = 0.f, o = -1e38f;
#pragma unroll
  for (int i = 0; i < CL / 2; ++i) {
#pragma unroll
    for (int h = 0; h < 2; ++h) {
      const float kt = h ? bhi(kp[i]) : blo(kp[i]);
      const float vt = h ? bhi(vp[i]) : blo(vp[i]);
      const float d = (w + o) - kt;                 // no2 = max(w+o, kt)
      const float e = __expf(-fabsf(d));
      const float A2 = (d < 0.f) ? e : 1.f;
      const float B2 = (d < 0.f) ? 1.f : e;
      p = A2 * p + B2 * vt;
      q = A2 * q + B2;
      o = fmaxf(w + o, kt);
    }
  }
  ps[j][ci] = p; qs[j][ci] = q; os[j][ci] = o;
  __syncthreads();

  // ---- phase 2: Kogge-Stone inclusive scan over chunks (4 steps) ----
#pragma unroll
  for (int s = 1; s < NCH; s <<= 1) {
    float P = p, Q = q, O = o;
    if (j >= s) {
      const float lp = ps[j - s][ci], lq = qs[j - s][ci], lo = os[j - s][ci];
      const float dsp = w * (float)(s * CL) + lo;   // left state decayed across span
      const float dd = dsp - o;
      const float e = __expf(-fabsf(dd));
      const float ea = (dd < 0.f) ? e : 1.f;
      const float eb = (dd < 0.f) ? 1.f : e;
      P = ea * lp + eb * p;
      Q = ea * lq + eb * q;
      O = fmaxf(dsp, o);
    }
    __syncthreads();
    p = P; q = Q; o = O;
    ps[j][ci] = p; qs[j][ci] = q; os[j][ci] = o;
    __syncthreads();
  }

  // ---- phase 3: re-scan from registers with exclusive prefix; emit z ----
  float pp = 0.f, qq = 0.f, oo = -1e38f;
  if (j > 0) { pp = ps[j - 1][ci]; qq = qs[j - 1][ci]; oo = os[j - 1][ci]; }

  size_t idx = base;
#pragma unroll
  for (int i = 0; i < CL / 2; ++i) {
#pragma unroll
    for (int h = 0; h < 2; ++h) {
      const float kt = h ? bhi(kp[i]) : blo(kp[i]);
      const float vt = h ? bhi(vp[i]) : blo(vp[i]);
      const float rt = b2f(rin[idx]);

      const float d1 = oo - (u + kt);               // no = max(oo, u+kt)
      const float e1 = __expf(-fabsf(d1));
      const float Ae = (d1 < 0.f) ? e1 : 1.f;
      const float Be = (d1 < 0.f) ? 1.f : e1;
      const float er = __expf(-rt);
      const float ysr = __fdividef(Ae * pp + Be * vt, (Ae * qq + Be) * (1.f + er));
      z[idx] = f2bf(ysr);

      const float d2 = (w + oo) - kt;               // no2 = max(w+oo, kt)
      const float e2 = __expf(-fabsf(d2));
      const float A2 = (d2 < 0.f) ? e2 : 1.f;
      const float B2 = (d2 < 0.f) ? 1.f : e2;
      pp = A2 * pp + B2 * vt;
      qq = A2 * qq + B2;
      oo = fmaxf(w + oo, kt);

      idx += C_;
    }
  }
}

// ---------------------------------------------------------------------------
extern "C" void kernel_launch(void* const* d_in, const int* in_sizes, int n_in,
                              void* d_out, int out_size, void* d_ws,
                              size_t ws_size, hipStream_t stream) {
  const float* x   = (const float*)d_in[0];
  const float* td  = (const float*)d_in[1];
  const float* tf  = (const float*)d_in[2];
  const float* tmk = (const float*)d_in[3];
  const float* tmv = (const float*)d_in[4];
  const float* tmr = (const float*)d_in[5];
  const float* Wk  = (const float*)d_in[6];
  const float* Wv  = (const float*)d_in[7];
  const float* Wr  = (const float*)d_in[8];
  const float* Wo  = (const float*)d_in[9];

  const size_t nW = (size_t)C_ * C_;
  const size_t nM = (size_t)M_ * C_;

  // ws (244.5 MiB): [wbk wbv wbr wbo][xk][xv][xr][kbuf][vbuf]  (all bf16)
  // rbuf lives in d_out (bf16; consumed by wkv before final GEMM overwrites)
  // z overlays xv (dead after gemm_v)
  unsigned short* wbk  = (unsigned short*)d_ws;
  unsigned short* wbv  = wbk + nW;
  unsigned short* wbr  = wbv + nW;
  unsigned short* wbo  = wbr + nW;
  unsigned short* xk   = wbo + nW;
  unsigned short* xv   = xk + nM;
  unsigned short* xr   = xv + nM;
  unsigned short* kbuf = xr + nM;
  unsigned short* vbuf = kbuf + nM;
  unsigned short* rbuf = (unsigned short*)d_out;
  unsigned short* zb   = xv;   // reuse

  cvt4_bf16<<<dim3((unsigned)(nW / 8 / 256), 4), 256, 0, stream>>>(
      Wk, Wv, Wr, Wo, wbk, wbv, wbr, wbo);

  const int mgrid = (int)(nM / 8 / 256);
  mix3_bf16<<<mgrid, 256, 0, stream>>>(x, tmk, tmv, tmr, xk, xv, xr);

  gemm8<1><<<GNB, 512, 0, stream>>>(xk, wbk, kbuf);   // xk dies
  gemm8<1><<<GNB, 512, 0, stream>>>(xv, wbv, vbuf);   // xv dies
  gemm8<1><<<GNB, 512, 0, stream>>>(xr, wbr, rbuf);   // -> d_out (bf16)

  wkv_scan<<<B_ * (C_ / CGRP), 512, 0, stream>>>(kbuf, vbuf, rbuf, td, tf, zb);

  gemm8<0><<<GNB, 512, 0, stream>>>(zb, wbo, d_out);  // f32 out
}

// Round 10
// 370.711 us; speedup vs baseline: 1.3952x; 1.3952x over previous
//
#include <hip/hip_runtime.h>
#include <math.h>

#define B_ 32
#define T_ 1024
#define C_ 768
#define M_ (B_ * T_)   // 32768

typedef __attribute__((ext_vector_type(8))) short bf16x8;
typedef __attribute__((ext_vector_type(4))) float f32x4;
typedef __attribute__((ext_vector_type(8))) unsigned short u16x8;
typedef __attribute__((address_space(1))) const void g_void;
typedef __attribute__((address_space(3))) void lds_void;

__device__ __forceinline__ unsigned short f2bf(float f) {
  union { float f; unsigned int u; } v; v.f = f;
  unsigned int u = v.u;
  u += 0x7fffu + ((u >> 16) & 1u);   // RNE
  return (unsigned short)(u >> 16);
}
__device__ __forceinline__ float b2f(unsigned short h) {
  union { unsigned int u; float f; } v; v.u = ((unsigned int)h) << 16;
  return v.f;
}

// ---------------------------------------------------------------------------
// Fused time-shift mix: read x once, emit xk, xv, xr (bf16)
// ---------------------------------------------------------------------------
__global__ __launch_bounds__(256) void mix3_bf16(const float* __restrict__ x,
                                                 const float* __restrict__ tmk,
                                                 const float* __restrict__ tmv,
                                                 const float* __restrict__ tmr,
                                                 unsigned short* __restrict__ ok,
                                                 unsigned short* __restrict__ ov,
                                                 unsigned short* __restrict__ orr) {
  const unsigned int gi = blockIdx.x * 256u + threadIdx.x;  // group of 8 elems
  const int m = gi / (C_ / 8);
  const int c8 = (gi % (C_ / 8)) * 8;
  const float* xp = x + (size_t)m * C_ + c8;
  float xv8[8], xx8[8], t8[8];
  *(float4*)&xv8[0] = *(const float4*)xp;
  *(float4*)&xv8[4] = *(const float4*)(xp + 4);
  if ((m & (T_ - 1)) != 0) {
    *(float4*)&xx8[0] = *(const float4*)(xp - C_);
    *(float4*)&xx8[4] = *(const float4*)(xp - C_ + 4);
  } else {
#pragma unroll
    for (int i = 0; i < 8; ++i) xx8[i] = 0.f;
  }
  const size_t ob = (size_t)m * C_ + c8;

  *(float4*)&t8[0] = *(const float4*)(tmk + c8);
  *(float4*)&t8[4] = *(const float4*)(tmk + c8 + 4);
  u16x8 o;
#pragma unroll
  for (int i = 0; i < 8; ++i) o[i] = f2bf(xv8[i] * t8[i] + xx8[i] * (1.f - t8[i]));
  *(u16x8*)(ok + ob) = o;

  *(float4*)&t8[0] = *(const float4*)(tmv + c8);
  *(float4*)&t8[4] = *(const float4*)(tmv + c8 + 4);
#pragma unroll
  for (int i = 0; i < 8; ++i) o[i] = f2bf(xv8[i] * t8[i] + xx8[i] * (1.f - t8[i]));
  *(u16x8*)(ov + ob) = o;

  *(float4*)&t8[0] = *(const float4*)(tmr + c8);
  *(float4*)&t8[4] = *(const float4*)(tmr + c8 + 4);
#pragma unroll
  for (int i = 0; i < 8; ++i) o[i] = f2bf(xv8[i] * t8[i] + xx8[i] * (1.f - t8[i]));
  *(u16x8*)(orr + ob) = o;
}

// f32 -> bf16 for all 4 weight matrices in one launch (blockIdx.y selects)
__global__ __launch_bounds__(256) void cvt4_bf16(const float* __restrict__ s0,
                                                 const float* __restrict__ s1,
                                                 const float* __restrict__ s2,
                                                 const float* __restrict__ s3,
                                                 unsigned short* __restrict__ d0,
                                                 unsigned short* __restrict__ d1,
                                                 unsigned short* __restrict__ d2,
                                                 unsigned short* __restrict__ d3) {
  const float* src = (blockIdx.y == 0) ? s0 : (blockIdx.y == 1) ? s1
                     : (blockIdx.y == 2) ? s2 : s3;
  unsigned short* dst = (blockIdx.y == 0) ? d0 : (blockIdx.y == 1) ? d1
                        : (blockIdx.y == 2) ? d2 : d3;
  const int gi = blockIdx.x * 256 + threadIdx.x;
  const float* p = src + (size_t)gi * 8;
  float v[8];
  *(float4*)&v[0] = *(const float4*)p;
  *(float4*)&v[4] = *(const float4*)(p + 4);
  u16x8 o;
#pragma unroll
  for (int i = 0; i < 8; ++i) o[i] = f2bf(v[i]);
  *(u16x8*)(dst + (size_t)gi * 8) = o;
}

// ---------------------------------------------------------------------------
// Pipelined bf16 GEMM: out[m][n] = sum_k A[m][k] * W[n][k]
// BM=256 x BN=128 tile, BK=64, 8 waves (2M x 4N), wave tile 128x32.
// Triple-buffered LDS K-tiles (144 KiB, 1 block/CU), depth-3 prefetch,
// counted vmcnt (12 -> 6 -> 0), raw s_barrier, T2 XOR swizzle both sides,
// T5 setprio around MFMA cluster.  (round-7 proven)
// ---------------------------------------------------------------------------
#define GBM 256
#define GBN 128
#define GBK 64
#define GNB ((M_ / GBM) * (C_ / GBN))  // 128*6 = 768
#define NT (C_ / GBK)                  // 12 K-tiles
#define BUFSZ 24576                    // shorts per buffer (A 16384 + B 8192)
#define BOFF_B 16384

#define WAITV(n) asm volatile("s_waitcnt vmcnt(" #n ")" ::: "memory")

template <int OUT_BF16>
__global__ __launch_bounds__(512) void gemm8(const unsigned short* __restrict__ A,
                                             const unsigned short* __restrict__ W,
                                             void* __restrict__ outv) {
  __shared__ unsigned short lds[3 * BUFSZ];   // 147456 B

  int bid = (int)blockIdx.x;
  bid = (bid & 7) * (GNB / 8) + (bid >> 3);   // bijective: 768 % 8 == 0
  const int mt = bid / (C_ / GBN);
  const int nt = bid % (C_ / GBN);
  const int m0 = mt * GBM, n0 = nt * GBN;

  const int tid = threadIdx.x;
  const int lane = tid & 63;
  const int wv = tid >> 6;        // 0..7
  const int wm = wv >> 2;         // 0..1
  const int wn = wv & 3;          // 0..3

  // staging: pre-swizzled global source, linear LDS dest (rule #21)
  const int l3 = lane >> 3;
  const int scol = (((lane & 7) ^ l3) << 3);   // element offset of 16B chunk
  const unsigned short* abase = A + (size_t)(m0 + wv * 8 + l3) * C_ + scol;
  const unsigned short* wbase = W + (size_t)(n0 + wv * 8 + l3) * C_ + scol;

#define STAGE(tt, bi)                                                         \
  {                                                                           \
    const int kk0_ = (tt) * GBK;                                              \
    _Pragma("unroll") for (int s_ = 0; s_ < 4; ++s_)                          \
        __builtin_amdgcn_global_load_lds(                                     \
            (g_void*)(abase + (size_t)s_ * 64 * C_ + kk0_),                   \
            (lds_void*)&lds[(bi) * BUFSZ + s_ * 4096 + wv * 512], 16, 0, 0);  \
    _Pragma("unroll") for (int s_ = 0; s_ < 2; ++s_)                          \
        __builtin_amdgcn_global_load_lds(                                     \
            (g_void*)(wbase + (size_t)s_ * 64 * C_ + kk0_),                   \
            (lds_void*)&lds[(bi) * BUFSZ + BOFF_B + s_ * 4096 + wv * 512],    \
            16, 0, 0);                                                        \
  }

  STAGE(0, 0);
  STAGE(1, 1);
  STAGE(2, 2);

  f32x4 acc[8][2] = {};
  const int arow = wm * 128 + (lane & 15);
  const int brow = wn * 32 + (lane & 15);

  int bufc = 0;
  for (int t = 0; t < NT; ++t) {
    if (t < NT - 2) { WAITV(12); }
    else if (t == NT - 2) { WAITV(6); }
    else { WAITV(0); }
    __builtin_amdgcn_s_barrier();
    __builtin_amdgcn_sched_barrier(0);

    const unsigned short* bufA = &lds[bufc * BUFSZ];
    const unsigned short* bufB = bufA + BOFF_B;

#pragma unroll
    for (int kk = 0; kk < 2; ++kk) {
      const int sw = ((((kk << 2) | (lane >> 4)) ^ (lane & 7)) << 3);
      bf16x8 af[8], bfv[2];
#pragma unroll
      for (int f = 0; f < 8; ++f)
        af[f] = *(const bf16x8*)&bufA[(arow + f * 16) * 64 + sw];
#pragma unroll
      for (int f = 0; f < 2; ++f)
        bfv[f] = *(const bf16x8*)&bufB[(brow + f * 16) * 64 + sw];
      __builtin_amdgcn_s_setprio(1);
#pragma unroll
      for (int i = 0; i < 8; ++i)
#pragma unroll
        for (int j = 0; j < 2; ++j)
          acc[i][j] = __builtin_amdgcn_mfma_f32_16x16x32_bf16(af[i], bfv[j], acc[i][j], 0, 0, 0);
      __builtin_amdgcn_s_setprio(0);
    }

    __builtin_amdgcn_s_barrier();
    __builtin_amdgcn_sched_barrier(0);
    if (t + 3 < NT) STAGE(t + 3, bufc);
    bufc = (bufc == 2) ? 0 : bufc + 1;
  }

  const int crow0 = m0 + wm * 128 + (lane >> 4) * 4;
  const int ccol0 = n0 + wn * 32 + (lane & 15);
  if (OUT_BF16) {
    unsigned short* out = (unsigned short*)outv;
#pragma unroll
    for (int i = 0; i < 8; ++i)
#pragma unroll
      for (int j = 0; j < 2; ++j)
#pragma unroll
        for (int r = 0; r < 4; ++r)
          out[(size_t)(crow0 + i * 16 + r) * C_ + ccol0 + j * 16] = f2bf(acc[i][j][r]);
  } else {
    float* out = (float*)outv;
#pragma unroll
    for (int i = 0; i < 8; ++i)
#pragma unroll
      for (int j = 0; j < 2; ++j)
#pragma unroll
        for (int r = 0; r < 4; ++r)
          out[(size_t)(crow0 + i * 16 + r) * C_ + ccol0 + j * 16] = acc[i][j][r];
  }
#undef STAGE
}

// ---------------------------------------------------------------------------
// WKV chunked associative scan -- STREAMING (round-4 structure, proven
// 92 us / VGPR 28 / no spill) + round-5 exp-halving math (4 exp + 1 div
// per element instead of 7 exp + 2 div).
// Register-cache arc (r5/r7/r8/r9) closed: flat-512/1024 workgroups never
// get enough VGPRs for a 32-64-reg cache; all variants spilled.
// Block: NCH=16 chunks x CGRP=32 channels = 512 threads. Grid 768.
// ---------------------------------------------------------------------------
#define NCH 16
#define CL  (T_ / NCH)   // 64
#define CGRP 32

__global__ __launch_bounds__(512) void wkv_scan(const unsigned short* __restrict__ kin,
                                                const unsigned short* __restrict__ vin,
                                                const unsigned short* __restrict__ rin,
                                                const float* __restrict__ wdec,
                                                const float* __restrict__ ufirst,
                                                unsigned short* __restrict__ z) {
  __shared__ float ps[NCH][CGRP], qs[NCH][CGRP], os[NCH][CGRP];

  const int b = blockIdx.x / (C_ / CGRP);
  const int cg = blockIdx.x % (C_ / CGRP);
  const int ci = threadIdx.x & (CGRP - 1);
  const int j = threadIdx.x >> 5;            // chunk 0..15
  const int c = cg * CGRP + ci;
  const float w = wdec[c], u = ufirst[c];
  const size_t base = ((size_t)b * T_ + (size_t)j * CL) * C_ + c;

  // ---- phase 1: local chunk scan, streaming k,v ----
  float p = 0.f, q = 0.f, o = -1e38f;
  {
    size_t idx = base;
#pragma unroll 8
    for (int t = 0; t < CL; ++t, idx += C_) {
      const float kt = b2f(kin[idx]);
      const float vt = b2f(vin[idx]);
      const float d = (w + o) - kt;                 // no2 = max(w+o, kt)
      const float e = __expf(-fabsf(d));
      const float A2 = (d < 0.f) ? e : 1.f;
      const float B2 = (d < 0.f) ? 1.f : e;
      p = A2 * p + B2 * vt;
      q = A2 * q + B2;
      o = fmaxf(w + o, kt);
    }
  }
  ps[j][ci] = p; qs[j][ci] = q; os[j][ci] = o;
  __syncthreads();

  // ---- phase 2: Kogge-Stone inclusive scan over chunks (4 steps) ----
#pragma unroll
  for (int s = 1; s < NCH; s <<= 1) {
    float P = p, Q = q, O = o;
    if (j >= s) {
      const float lp = ps[j - s][ci], lq = qs[j - s][ci], lo = os[j - s][ci];
      const float dsp = w * (float)(s * CL) + lo;   // left state decayed across span
      const float dd = dsp - o;
      const float e = __expf(-fabsf(dd));
      const float ea = (dd < 0.f) ? e : 1.f;
      const float eb = (dd < 0.f) ? 1.f : e;
      P = ea * lp + eb * p;
      Q = ea * lq + eb * q;
      O = fmaxf(dsp, o);
    }
    __syncthreads();
    p = P; q = Q; o = O;
    ps[j][ci] = p; qs[j][ci] = q; os[j][ci] = o;
    __syncthreads();
  }

  // ---- phase 3: re-scan with exclusive prefix, streaming k,v,r; emit z ----
  float pp = 0.f, qq = 0.f, oo = -1e38f;
  if (j > 0) { pp = ps[j - 1][ci]; qq = qs[j - 1][ci]; oo = os[j - 1][ci]; }

  size_t idx = base;
#pragma unroll 4
  for (int t = 0; t < CL; ++t, idx += C_) {
    const float kt = b2f(kin[idx]);
    const float vt = b2f(vin[idx]);
    const float rt = b2f(rin[idx]);

    const float d1 = oo - (u + kt);                 // no = max(oo, u+kt)
    const float e1 = __expf(-fabsf(d1));
    const float Ae = (d1 < 0.f) ? e1 : 1.f;
    const float Be = (d1 < 0.f) ? 1.f : e1;
    const float er = __expf(-rt);
    const float ysr = __fdividef(Ae * pp + Be * vt, (Ae * qq + Be) * (1.f + er));
    z[idx] = f2bf(ysr);

    const float d2 = (w + oo) - kt;                 // no2 = max(w+oo, kt)
    const float e2 = __expf(-fabsf(d2));
    const float A2 = (d2 < 0.f) ? e2 : 1.f;
    const float B2 = (d2 < 0.f) ? 1.f : e2;
    pp = A2 * pp + B2 * vt;
    qq = A2 * qq + B2;
    oo = fmaxf(w + oo, kt);
  }
}

// ---------------------------------------------------------------------------
extern "C" void kernel_launch(void* const* d_in, const int* in_sizes, int n_in,
                              void* d_out, int out_size, void* d_ws,
                              size_t ws_size, hipStream_t stream) {
  const float* x   = (const float*)d_in[0];
  const float* td  = (const float*)d_in[1];
  const float* tf  = (const float*)d_in[2];
  const float* tmk = (const float*)d_in[3];
  const float* tmv = (const float*)d_in[4];
  const float* tmr = (const float*)d_in[5];
  const float* Wk  = (const float*)d_in[6];
  const float* Wv  = (const float*)d_in[7];
  const float* Wr  = (const float*)d_in[8];
  const float* Wo  = (const float*)d_in[9];

  const size_t nW = (size_t)C_ * C_;
  const size_t nM = (size_t)M_ * C_;

  // ws (244.5 MiB): [wbk wbv wbr wbo][xk][xv][xr][kbuf][vbuf]  (all bf16)
  // rbuf lives in d_out (bf16; consumed by wkv before final GEMM overwrites)
  // z overlays xv (dead after gemm_v)
  unsigned short* wbk  = (unsigned short*)d_ws;
  unsigned short* wbv  = wbk + nW;
  unsigned short* wbr  = wbv + nW;
  unsigned short* wbo  = wbr + nW;
  unsigned short* xk   = wbo + nW;
  unsigned short* xv   = xk + nM;
  unsigned short* xr   = xv + nM;
  unsigned short* kbuf = xr + nM;
  unsigned short* vbuf = kbuf + nM;
  unsigned short* rbuf = (unsigned short*)d_out;
  unsigned short* zb   = xv;   // reuse

  cvt4_bf16<<<dim3((unsigned)(nW / 8 / 256), 4), 256, 0, stream>>>(
      Wk, Wv, Wr, Wo, wbk, wbv, wbr, wbo);

  const int mgrid = (int)(nM / 8 / 256);
  mix3_bf16<<<mgrid, 256, 0, stream>>>(x, tmk, tmv, tmr, xk, xv, xr);

  gemm8<1><<<GNB, 512, 0, stream>>>(xk, wbk, kbuf);   // xk dies
  gemm8<1><<<GNB, 512, 0, stream>>>(xv, wbv, vbuf);   // xv dies
  gemm8<1><<<GNB, 512, 0, stream>>>(xr, wbr, rbuf);   // -> d_out (bf16)

  wkv_scan<<<B_ * (C_ / CGRP), 512, 0, stream>>>(kbuf, vbuf, rbuf, td, tf, zb);

  gemm8<0><<<GNB, 512, 0, stream>>>(zb, wbo, d_out);  // f32 out
}

// Round 12
// 362.459 us; speedup vs baseline: 1.4270x; 1.0228x over previous
//
#include <hip/hip_runtime.h>
#include <math.h>

#define B_ 32
#define T_ 1024
#define C_ 768
#define M_ (B_ * T_)   // 32768

typedef __attribute__((ext_vector_type(8))) short bf16x8;
typedef __attribute__((ext_vector_type(4))) float f32x4;
typedef __attribute__((ext_vector_type(8))) unsigned short u16x8;
typedef __attribute__((address_space(1))) const void g_void;
typedef __attribute__((address_space(3))) void lds_void;

__device__ __forceinline__ unsigned short f2bf(float f) {
  union { float f; unsigned int u; } v; v.f = f;
  unsigned int u = v.u;
  u += 0x7fffu + ((u >> 16) & 1u);   // RNE
  return (unsigned short)(u >> 16);
}
__device__ __forceinline__ float b2f(unsigned short h) {
  union { unsigned int u; float f; } v; v.u = ((unsigned int)h) << 16;
  return v.f;
}

// ---------------------------------------------------------------------------
// prep: fused {4x weight f32->bf16 convert} + {time-shift mix x->xk,xv,xr}
// blocks [0, WBLK): weights; blocks [WBLK, WBLK+MBLK): mix.
// WBLK = 4 matrices x 288 blocks each (288 = 589824 elem / 2048 per block).
// (round-11 bug: WBLK was 288 total -> 75% of weights stayed poison)
// ---------------------------------------------------------------------------
#define WPB 288                      // blocks per weight matrix
#define WBLK (4 * WPB)               // 1152
#define MBLK ((M_ * C_ / 8) / 256)   // 12288

__global__ __launch_bounds__(256) void prep(const float* __restrict__ x,
                                            const float* __restrict__ tmk,
                                            const float* __restrict__ tmv,
                                            const float* __restrict__ tmr,
                                            const float* __restrict__ Wk,
                                            const float* __restrict__ Wv,
                                            const float* __restrict__ Wr,
                                            const float* __restrict__ Wo,
                                            unsigned short* __restrict__ wbk,
                                            unsigned short* __restrict__ wbv,
                                            unsigned short* __restrict__ wbr,
                                            unsigned short* __restrict__ wbo,
                                            unsigned short* __restrict__ ok,
                                            unsigned short* __restrict__ ov,
                                            unsigned short* __restrict__ orr) {
  if (blockIdx.x < WBLK) {
    const int sel = blockIdx.x / WPB;              // 0..3
    const int wi = blockIdx.x % WPB;
    const float* src = (sel == 0) ? Wk : (sel == 1) ? Wv : (sel == 2) ? Wr : Wo;
    unsigned short* dst = (sel == 0) ? wbk : (sel == 1) ? wbv : (sel == 2) ? wbr : wbo;
    const int gi = wi * 256 + threadIdx.x;
    const float* p = src + (size_t)gi * 8;
    float v[8];
    *(float4*)&v[0] = *(const float4*)p;
    *(float4*)&v[4] = *(const float4*)(p + 4);
    u16x8 o;
#pragma unroll
    for (int i = 0; i < 8; ++i) o[i] = f2bf(v[i]);
    *(u16x8*)(dst + (size_t)gi * 8) = o;
    return;
  }

  const unsigned int gi = (blockIdx.x - WBLK) * 256u + threadIdx.x;
  const int m = gi / (C_ / 8);
  const int c8 = (gi % (C_ / 8)) * 8;
  const float* xp = x + (size_t)m * C_ + c8;
  float xv8[8], xx8[8], t8[8];
  *(float4*)&xv8[0] = *(const float4*)xp;
  *(float4*)&xv8[4] = *(const float4*)(xp + 4);
  if ((m & (T_ - 1)) != 0) {
    *(float4*)&xx8[0] = *(const float4*)(xp - C_);
    *(float4*)&xx8[4] = *(const float4*)(xp - C_ + 4);
  } else {
#pragma unroll
    for (int i = 0; i < 8; ++i) xx8[i] = 0.f;
  }
  const size_t ob = (size_t)m * C_ + c8;

  *(float4*)&t8[0] = *(const float4*)(tmk + c8);
  *(float4*)&t8[4] = *(const float4*)(tmk + c8 + 4);
  u16x8 o;
#pragma unroll
  for (int i = 0; i < 8; ++i) o[i] = f2bf(xv8[i] * t8[i] + xx8[i] * (1.f - t8[i]));
  *(u16x8*)(ok + ob) = o;

  *(float4*)&t8[0] = *(const float4*)(tmv + c8);
  *(float4*)&t8[4] = *(const float4*)(tmv + c8 + 4);
#pragma unroll
  for (int i = 0; i < 8; ++i) o[i] = f2bf(xv8[i] * t8[i] + xx8[i] * (1.f - t8[i]));
  *(u16x8*)(ov + ob) = o;

  *(float4*)&t8[0] = *(const float4*)(tmr + c8);
  *(float4*)&t8[4] = *(const float4*)(tmr + c8 + 4);
#pragma unroll
  for (int i = 0; i < 8; ++i) o[i] = f2bf(xv8[i] * t8[i] + xx8[i] * (1.f - t8[i]));
  *(u16x8*)(orr + ob) = o;
}

// ---------------------------------------------------------------------------
// Pipelined bf16 GEMM (round-7 proven, unchanged): BM=256 x BN=128, BK=64,
// 8 waves, triple-buffered LDS, counted vmcnt 12/6/0, raw s_barrier,
// XOR swizzle both sides, setprio around MFMA.
// ---------------------------------------------------------------------------
#define GBM 256
#define GBN 128
#define GBK 64
#define GNB ((M_ / GBM) * (C_ / GBN))  // 768
#define NT (C_ / GBK)                  // 12
#define BUFSZ 24576
#define BOFF_B 16384

#define WAITV(n) asm volatile("s_waitcnt vmcnt(" #n ")" ::: "memory")

template <int OUT_BF16>
__global__ __launch_bounds__(512) void gemm8(const unsigned short* __restrict__ A,
                                             const unsigned short* __restrict__ W,
                                             void* __restrict__ outv) {
  __shared__ unsigned short lds[3 * BUFSZ];

  int bid = (int)blockIdx.x;
  bid = (bid & 7) * (GNB / 8) + (bid >> 3);
  const int mt = bid / (C_ / GBN);
  const int nt = bid % (C_ / GBN);
  const int m0 = mt * GBM, n0 = nt * GBN;

  const int tid = threadIdx.x;
  const int lane = tid & 63;
  const int wv = tid >> 6;
  const int wm = wv >> 2;
  const int wn = wv & 3;

  const int l3 = lane >> 3;
  const int scol = (((lane & 7) ^ l3) << 3);
  const unsigned short* abase = A + (size_t)(m0 + wv * 8 + l3) * C_ + scol;
  const unsigned short* wbase = W + (size_t)(n0 + wv * 8 + l3) * C_ + scol;

#define STAGE(tt, bi)                                                         \
  {                                                                           \
    const int kk0_ = (tt) * GBK;                                              \
    _Pragma("unroll") for (int s_ = 0; s_ < 4; ++s_)                          \
        __builtin_amdgcn_global_load_lds(                                     \
            (g_void*)(abase + (size_t)s_ * 64 * C_ + kk0_),                   \
            (lds_void*)&lds[(bi) * BUFSZ + s_ * 4096 + wv * 512], 16, 0, 0);  \
    _Pragma("unroll") for (int s_ = 0; s_ < 2; ++s_)                          \
        __builtin_amdgcn_global_load_lds(                                     \
            (g_void*)(wbase + (size_t)s_ * 64 * C_ + kk0_),                   \
            (lds_void*)&lds[(bi) * BUFSZ + BOFF_B + s_ * 4096 + wv * 512],    \
            16, 0, 0);                                                        \
  }

  STAGE(0, 0);
  STAGE(1, 1);
  STAGE(2, 2);

  f32x4 acc[8][2] = {};
  const int arow = wm * 128 + (lane & 15);
  const int brow = wn * 32 + (lane & 15);

  int bufc = 0;
  for (int t = 0; t < NT; ++t) {
    if (t < NT - 2) { WAITV(12); }
    else if (t == NT - 2) { WAITV(6); }
    else { WAITV(0); }
    __builtin_amdgcn_s_barrier();
    __builtin_amdgcn_sched_barrier(0);

    const unsigned short* bufA = &lds[bufc * BUFSZ];
    const unsigned short* bufB = bufA + BOFF_B;

#pragma unroll
    for (int kk = 0; kk < 2; ++kk) {
      const int sw = ((((kk << 2) | (lane >> 4)) ^ (lane & 7)) << 3);
      bf16x8 af[8], bfv[2];
#pragma unroll
      for (int f = 0; f < 8; ++f)
        af[f] = *(const bf16x8*)&bufA[(arow + f * 16) * 64 + sw];
#pragma unroll
      for (int f = 0; f < 2; ++f)
        bfv[f] = *(const bf16x8*)&bufB[(brow + f * 16) * 64 + sw];
      __builtin_amdgcn_s_setprio(1);
#pragma unroll
      for (int i = 0; i < 8; ++i)
#pragma unroll
        for (int j = 0; j < 2; ++j)
          acc[i][j] = __builtin_amdgcn_mfma_f32_16x16x32_bf16(af[i], bfv[j], acc[i][j], 0, 0, 0);
      __builtin_amdgcn_s_setprio(0);
    }

    __builtin_amdgcn_s_barrier();
    __builtin_amdgcn_sched_barrier(0);
    if (t + 3 < NT) STAGE(t + 3, bufc);
    bufc = (bufc == 2) ? 0 : bufc + 1;
  }

  const int crow0 = m0 + wm * 128 + (lane >> 4) * 4;
  const int ccol0 = n0 + wn * 32 + (lane & 15);
  if (OUT_BF16) {
    unsigned short* out = (unsigned short*)outv;
#pragma unroll
    for (int i = 0; i < 8; ++i)
#pragma unroll
      for (int j = 0; j < 2; ++j)
#pragma unroll
        for (int r = 0; r < 4; ++r)
          out[(size_t)(crow0 + i * 16 + r) * C_ + ccol0 + j * 16] = f2bf(acc[i][j][r]);
  } else {
    float* out = (float*)outv;
#pragma unroll
    for (int i = 0; i < 8; ++i)
#pragma unroll
      for (int j = 0; j < 2; ++j)
#pragma unroll
        for (int r = 0; r < 4; ++r)
          out[(size_t)(crow0 + i * 16 + r) * C_ + ccol0 + j * 16] = acc[i][j][r];
  }
#undef STAGE
}

// ---------------------------------------------------------------------------
// WKV chunked associative scan -- STREAMING math (round-10 proven), 1024
// threads: NCH=32 chunks of CL=32, CGRP=32 channels (round-6 proven shape).
// Streaming needs only ~24-32 VGPRs so the flat-1024 64-VGPR cap is
// harmless; 16 waves/block doubles TLP, halves serial chain per phase.
// ---------------------------------------------------------------------------
#define NCH 32
#define CL  (T_ / NCH)   // 32
#define CGRP 32

__global__ __launch_bounds__(1024) void wkv_scan(const unsigned short* __restrict__ kin,
                                                 const unsigned short* __restrict__ vin,
                                                 const unsigned short* __restrict__ rin,
                                                 const float* __restrict__ wdec,
                                                 const float* __restrict__ ufirst,
                                                 unsigned short* __restrict__ z) {
  __shared__ float ps[NCH][CGRP], qs[NCH][CGRP], os[NCH][CGRP];

  const int b = blockIdx.x / (C_ / CGRP);
  const int cg = blockIdx.x % (C_ / CGRP);
  const int ci = threadIdx.x & (CGRP - 1);
  const int j = threadIdx.x >> 5;            // chunk 0..31
  const int c = cg * CGRP + ci;
  const float w = wdec[c], u = ufirst[c];
  const size_t base = ((size_t)b * T_ + (size_t)j * CL) * C_ + c;

  // ---- phase 1: local chunk scan, streaming k,v ----
  float p = 0.f, q = 0.f, o = -1e38f;
  {
    size_t idx = base;
#pragma unroll 4
    for (int t = 0; t < CL; ++t, idx += C_) {
      const float kt = b2f(kin[idx]);
      const float vt = b2f(vin[idx]);
      const float d = (w + o) - kt;                 // no2 = max(w+o, kt)
      const float e = __expf(-fabsf(d));
      const float A2 = (d < 0.f) ? e : 1.f;
      const float B2 = (d < 0.f) ? 1.f : e;
      p = A2 * p + B2 * vt;
      q = A2 * q + B2;
      o = fmaxf(w + o, kt);
    }
  }
  ps[j][ci] = p; qs[j][ci] = q; os[j][ci] = o;
  __syncthreads();

  // ---- phase 2: Kogge-Stone inclusive scan over chunks (5 steps) ----
#pragma unroll
  for (int s = 1; s < NCH; s <<= 1) {
    float P = p, Q = q, O = o;
    if (j >= s) {
      const float lp = ps[j - s][ci], lq = qs[j - s][ci], lo = os[j - s][ci];
      const float dsp = w * (float)(s * CL) + lo;   // left state decayed across span
      const float dd = dsp - o;
      const float e = __expf(-fabsf(dd));
      const float ea = (dd < 0.f) ? e : 1.f;
      const float eb = (dd < 0.f) ? 1.f : e;
      P = ea * lp + eb * p;
      Q = ea * lq + eb * q;
      O = fmaxf(dsp, o);
    }
    __syncthreads();
    p = P; q = Q; o = O;
    ps[j][ci] = p; qs[j][ci] = q; os[j][ci] = o;
    __syncthreads();
  }

  // ---- phase 3: re-scan with exclusive prefix, streaming k,v,r; emit z ----
  float pp = 0.f, qq = 0.f, oo = -1e38f;
  if (j > 0) { pp = ps[j - 1][ci]; qq = qs[j - 1][ci]; oo = os[j - 1][ci]; }

  size_t idx = base;
#pragma unroll 4
  for (int t = 0; t < CL; ++t, idx += C_) {
    const float kt = b2f(kin[idx]);
    const float vt = b2f(vin[idx]);
    const float rt = b2f(rin[idx]);

    const float d1 = oo - (u + kt);                 // no = max(oo, u+kt)
    const float e1 = __expf(-fabsf(d1));
    const float Ae = (d1 < 0.f) ? e1 : 1.f;
    const float Be = (d1 < 0.f) ? 1.f : e1;
    const float er = __expf(-rt);
    const float ysr = __fdividef(Ae * pp + Be * vt, (Ae * qq + Be) * (1.f + er));
    z[idx] = f2bf(ysr);

    const float d2 = (w + oo) - kt;                 // no2 = max(w+oo, kt)
    const float e2 = __expf(-fabsf(d2));
    const float A2 = (d2 < 0.f) ? e2 : 1.f;
    const float B2 = (d2 < 0.f) ? 1.f : e2;
    pp = A2 * pp + B2 * vt;
    qq = A2 * qq + B2;
    oo = fmaxf(w + oo, kt);
  }
}

// ---------------------------------------------------------------------------
extern "C" void kernel_launch(void* const* d_in, const int* in_sizes, int n_in,
                              void* d_out, int out_size, void* d_ws,
                              size_t ws_size, hipStream_t stream) {
  const float* x   = (const float*)d_in[0];
  const float* td  = (const float*)d_in[1];
  const float* tf  = (const float*)d_in[2];
  const float* tmk = (const float*)d_in[3];
  const float* tmv = (const float*)d_in[4];
  const float* tmr = (const float*)d_in[5];
  const float* Wk  = (const float*)d_in[6];
  const float* Wv  = (const float*)d_in[7];
  const float* Wr  = (const float*)d_in[8];
  const float* Wo  = (const float*)d_in[9];

  const size_t nW = (size_t)C_ * C_;
  const size_t nM = (size_t)M_ * C_;

  // ws (244.5 MiB): [wbk wbv wbr wbo][xk][xv][xr][kbuf][vbuf]  (all bf16)
  // rbuf lives in d_out (bf16; consumed by wkv before final GEMM overwrites)
  // z overlays xv (dead after gemm_v)
  unsigned short* wbk  = (unsigned short*)d_ws;
  unsigned short* wbv  = wbk + nW;
  unsigned short* wbr  = wbv + nW;
  unsigned short* wbo  = wbr + nW;
  unsigned short* xk   = wbo + nW;
  unsigned short* xv   = xk + nM;
  unsigned short* xr   = xv + nM;
  unsigned short* kbuf = xr + nM;
  unsigned short* vbuf = kbuf + nM;
  unsigned short* rbuf = (unsigned short*)d_out;
  unsigned short* zb   = xv;   // reuse

  prep<<<WBLK + MBLK, 256, 0, stream>>>(x, tmk, tmv, tmr, Wk, Wv, Wr, Wo,
                                        wbk, wbv, wbr, wbo, xk, xv, xr);

  gemm8<1><<<GNB, 512, 0, stream>>>(xk, wbk, kbuf);   // xk dies
  gemm8<1><<<GNB, 512, 0, stream>>>(xv, wbv, vbuf);   // xv dies
  gemm8<1><<<GNB, 512, 0, stream>>>(xr, wbr, rbuf);   // -> d_out (bf16)

  wkv_scan<<<B_ * (C_ / CGRP), 1024, 0, stream>>>(kbuf, vbuf, rbuf, td, tf, zb);

  gemm8<0><<<GNB, 512, 0, stream>>>(zb, wbo, d_out);  // f32 out
}

// Round 13
// 351.500 us; speedup vs baseline: 1.4715x; 1.0312x over previous
//
#include <hip/hip_runtime.h>
#include <math.h>

#define B_ 32
#define T_ 1024
#define C_ 768
#define M_ (B_ * T_)   // 32768

typedef __attribute__((ext_vector_type(8))) short bf16x8;
typedef __attribute__((ext_vector_type(4))) float f32x4;
typedef __attribute__((ext_vector_type(8))) unsigned short u16x8;
typedef __attribute__((address_space(1))) const void g_void;
typedef __attribute__((address_space(3))) void lds_void;

__device__ __forceinline__ unsigned short f2bf(float f) {
  union { float f; unsigned int u; } v; v.f = f;
  unsigned int u = v.u;
  u += 0x7fffu + ((u >> 16) & 1u);   // RNE
  return (unsigned short)(u >> 16);
}
__device__ __forceinline__ float b2f(unsigned short h) {
  union { unsigned int u; float f; } v; v.u = ((unsigned int)h) << 16;
  return v.f;
}
__device__ __forceinline__ float blo(unsigned int p) {   // low bf16 of packed pair
  union { unsigned int u; float f; } v; v.u = p << 16;
  return v.f;
}
__device__ __forceinline__ float bhi(unsigned int p) {   // high bf16 of packed pair
  union { unsigned int u; float f; } v; v.u = p & 0xffff0000u;
  return v.f;
}

// ---------------------------------------------------------------------------
// prep: fused {4x weight f32->bf16 convert} + {time-shift mix x->xk,xv,xr}
// ---------------------------------------------------------------------------
#define WPB 288                      // blocks per weight matrix
#define WBLK (4 * WPB)               // 1152
#define MBLK ((M_ * C_ / 8) / 256)   // 12288

__global__ __launch_bounds__(256) void prep(const float* __restrict__ x,
                                            const float* __restrict__ tmk,
                                            const float* __restrict__ tmv,
                                            const float* __restrict__ tmr,
                                            const float* __restrict__ Wk,
                                            const float* __restrict__ Wv,
                                            const float* __restrict__ Wr,
                                            const float* __restrict__ Wo,
                                            unsigned short* __restrict__ wbk,
                                            unsigned short* __restrict__ wbv,
                                            unsigned short* __restrict__ wbr,
                                            unsigned short* __restrict__ wbo,
                                            unsigned short* __restrict__ ok,
                                            unsigned short* __restrict__ ov,
                                            unsigned short* __restrict__ orr) {
  if (blockIdx.x < WBLK) {
    const int sel = blockIdx.x / WPB;              // 0..3
    const int wi = blockIdx.x % WPB;
    const float* src = (sel == 0) ? Wk : (sel == 1) ? Wv : (sel == 2) ? Wr : Wo;
    unsigned short* dst = (sel == 0) ? wbk : (sel == 1) ? wbv : (sel == 2) ? wbr : wbo;
    const int gi = wi * 256 + threadIdx.x;
    const float* p = src + (size_t)gi * 8;
    float v[8];
    *(float4*)&v[0] = *(const float4*)p;
    *(float4*)&v[4] = *(const float4*)(p + 4);
    u16x8 o;
#pragma unroll
    for (int i = 0; i < 8; ++i) o[i] = f2bf(v[i]);
    *(u16x8*)(dst + (size_t)gi * 8) = o;
    return;
  }

  const unsigned int gi = (blockIdx.x - WBLK) * 256u + threadIdx.x;
  const int m = gi / (C_ / 8);
  const int c8 = (gi % (C_ / 8)) * 8;
  const float* xp = x + (size_t)m * C_ + c8;
  float xv8[8], xx8[8], t8[8];
  *(float4*)&xv8[0] = *(const float4*)xp;
  *(float4*)&xv8[4] = *(const float4*)(xp + 4);
  if ((m & (T_ - 1)) != 0) {
    *(float4*)&xx8[0] = *(const float4*)(xp - C_);
    *(float4*)&xx8[4] = *(const float4*)(xp - C_ + 4);
  } else {
#pragma unroll
    for (int i = 0; i < 8; ++i) xx8[i] = 0.f;
  }
  const size_t ob = (size_t)m * C_ + c8;

  *(float4*)&t8[0] = *(const float4*)(tmk + c8);
  *(float4*)&t8[4] = *(const float4*)(tmk + c8 + 4);
  u16x8 o;
#pragma unroll
  for (int i = 0; i < 8; ++i) o[i] = f2bf(xv8[i] * t8[i] + xx8[i] * (1.f - t8[i]));
  *(u16x8*)(ok + ob) = o;

  *(float4*)&t8[0] = *(const float4*)(tmv + c8);
  *(float4*)&t8[4] = *(const float4*)(tmv + c8 + 4);
#pragma unroll
  for (int i = 0; i < 8; ++i) o[i] = f2bf(xv8[i] * t8[i] + xx8[i] * (1.f - t8[i]));
  *(u16x8*)(ov + ob) = o;

  *(float4*)&t8[0] = *(const float4*)(tmr + c8);
  *(float4*)&t8[4] = *(const float4*)(tmr + c8 + 4);
#pragma unroll
  for (int i = 0; i < 8; ++i) o[i] = f2bf(xv8[i] * t8[i] + xx8[i] * (1.f - t8[i]));
  *(u16x8*)(orr + ob) = o;
}

// ---------------------------------------------------------------------------
// Pipelined bf16 GEMM (round-7 proven, unchanged)
// ---------------------------------------------------------------------------
#define GBM 256
#define GBN 128
#define GBK 64
#define GNB ((M_ / GBM) * (C_ / GBN))  // 768
#define NT (C_ / GBK)                  // 12
#define BUFSZ 24576
#define BOFF_B 16384

#define WAITV(n) asm volatile("s_waitcnt vmcnt(" #n ")" ::: "memory")

template <int OUT_BF16>
__global__ __launch_bounds__(512) void gemm8(const unsigned short* __restrict__ A,
                                             const unsigned short* __restrict__ W,
                                             void* __restrict__ outv) {
  __shared__ unsigned short lds[3 * BUFSZ];

  int bid = (int)blockIdx.x;
  bid = (bid & 7) * (GNB / 8) + (bid >> 3);
  const int mt = bid / (C_ / GBN);
  const int nt = bid % (C_ / GBN);
  const int m0 = mt * GBM, n0 = nt * GBN;

  const int tid = threadIdx.x;
  const int lane = tid & 63;
  const int wv = tid >> 6;
  const int wm = wv >> 2;
  const int wn = wv & 3;

  const int l3 = lane >> 3;
  const int scol = (((lane & 7) ^ l3) << 3);
  const unsigned short* abase = A + (size_t)(m0 + wv * 8 + l3) * C_ + scol;
  const unsigned short* wbase = W + (size_t)(n0 + wv * 8 + l3) * C_ + scol;

#define STAGE(tt, bi)                                                         \
  {                                                                           \
    const int kk0_ = (tt) * GBK;                                              \
    _Pragma("unroll") for (int s_ = 0; s_ < 4; ++s_)                          \
        __builtin_amdgcn_global_load_lds(                                     \
            (g_void*)(abase + (size_t)s_ * 64 * C_ + kk0_),                   \
            (lds_void*)&lds[(bi) * BUFSZ + s_ * 4096 + wv * 512], 16, 0, 0);  \
    _Pragma("unroll") for (int s_ = 0; s_ < 2; ++s_)                          \
        __builtin_amdgcn_global_load_lds(                                     \
            (g_void*)(wbase + (size_t)s_ * 64 * C_ + kk0_),                   \
            (lds_void*)&lds[(bi) * BUFSZ + BOFF_B + s_ * 4096 + wv * 512],    \
            16, 0, 0);                                                        \
  }

  STAGE(0, 0);
  STAGE(1, 1);
  STAGE(2, 2);

  f32x4 acc[8][2] = {};
  const int arow = wm * 128 + (lane & 15);
  const int brow = wn * 32 + (lane & 15);

  int bufc = 0;
  for (int t = 0; t < NT; ++t) {
    if (t < NT - 2) { WAITV(12); }
    else if (t == NT - 2) { WAITV(6); }
    else { WAITV(0); }
    __builtin_amdgcn_s_barrier();
    __builtin_amdgcn_sched_barrier(0);

    const unsigned short* bufA = &lds[bufc * BUFSZ];
    const unsigned short* bufB = bufA + BOFF_B;

#pragma unroll
    for (int kk = 0; kk < 2; ++kk) {
      const int sw = ((((kk << 2) | (lane >> 4)) ^ (lane & 7)) << 3);
      bf16x8 af[8], bfv[2];
#pragma unroll
      for (int f = 0; f < 8; ++f)
        af[f] = *(const bf16x8*)&bufA[(arow + f * 16) * 64 + sw];
#pragma unroll
      for (int f = 0; f < 2; ++f)
        bfv[f] = *(const bf16x8*)&bufB[(brow + f * 16) * 64 + sw];
      __builtin_amdgcn_s_setprio(1);
#pragma unroll
      for (int i = 0; i < 8; ++i)
#pragma unroll
        for (int j = 0; j < 2; ++j)
          acc[i][j] = __builtin_amdgcn_mfma_f32_16x16x32_bf16(af[i], bfv[j], acc[i][j], 0, 0, 0);
      __builtin_amdgcn_s_setprio(0);
    }

    __builtin_amdgcn_s_barrier();
    __builtin_amdgcn_sched_barrier(0);
    if (t + 3 < NT) STAGE(t + 3, bufc);
    bufc = (bufc == 2) ? 0 : bufc + 1;
  }

  const int crow0 = m0 + wm * 128 + (lane >> 4) * 4;
  const int ccol0 = n0 + wn * 32 + (lane & 15);
  if (OUT_BF16) {
    unsigned short* out = (unsigned short*)outv;
#pragma unroll
    for (int i = 0; i < 8; ++i)
#pragma unroll
      for (int j = 0; j < 2; ++j)
#pragma unroll
        for (int r = 0; r < 4; ++r)
          out[(size_t)(crow0 + i * 16 + r) * C_ + ccol0 + j * 16] = f2bf(acc[i][j][r]);
  } else {
    float* out = (float*)outv;
#pragma unroll
    for (int i = 0; i < 8; ++i)
#pragma unroll
      for (int j = 0; j < 2; ++j)
#pragma unroll
        for (int r = 0; r < 4; ++r)
          out[(size_t)(crow0 + i * 16 + r) * C_ + ccol0 + j * 16] = acc[i][j][r];
  }
#undef STAGE
}

// ---------------------------------------------------------------------------
// WKV chunked associative scan -- STREAMING, 2 channels per thread.
// Packed 4B loads of k/v/r (2 bf16 = 2 adjacent channels) and packed 4B z
// stores halve memory-op count and give 2-way ILP on the exp chains.
// Block: NCH=32 chunks x 32 lanes (x2 channels) = 1024 threads / 64 channels.
// Grid: B x C/64 = 384. State is streaming-only (~50 VGPR < flat-1024 cap 64).
// ---------------------------------------------------------------------------
#define NCH 32
#define CL  (T_ / NCH)   // 32

__global__ __launch_bounds__(1024) void wkv_scan(const unsigned short* __restrict__ kin,
                                                 const unsigned short* __restrict__ vin,
                                                 const unsigned short* __restrict__ rin,
                                                 const float* __restrict__ wdec,
                                                 const float* __restrict__ ufirst,
                                                 unsigned short* __restrict__ z) {
  __shared__ float ps[NCH][64], qs[NCH][64], os[NCH][64];

  const int b = blockIdx.x / (C_ / 64);
  const int cg = blockIdx.x % (C_ / 64);
  const int ci = threadIdx.x & 31;           // channel-pair index
  const int j = threadIdx.x >> 5;            // chunk 0..31
  const int c0 = cg * 64 + 2 * ci;
  const float w0 = wdec[c0], w1 = wdec[c0 + 1];
  const float u0 = ufirst[c0], u1 = ufirst[c0 + 1];
  const size_t base = ((size_t)b * T_ + (size_t)j * CL) * C_ + c0;

  // ---- phase 1: local chunk scan, packed streaming k,v ----
  float p0 = 0.f, q0 = 0.f, o0 = -1e38f;
  float p1 = 0.f, q1 = 0.f, o1 = -1e38f;
  {
    size_t idx = base;
#pragma unroll 4
    for (int t = 0; t < CL; ++t, idx += C_) {
      const unsigned int kk = *(const unsigned int*)(kin + idx);
      const unsigned int vv = *(const unsigned int*)(vin + idx);
      {
        const float kt = blo(kk), vt = blo(vv);
        const float d = (w0 + o0) - kt;
        const float e = __expf(-fabsf(d));
        const float A2 = (d < 0.f) ? e : 1.f;
        const float B2 = (d < 0.f) ? 1.f : e;
        p0 = A2 * p0 + B2 * vt;
        q0 = A2 * q0 + B2;
        o0 = fmaxf(w0 + o0, kt);
      }
      {
        const float kt = bhi(kk), vt = bhi(vv);
        const float d = (w1 + o1) - kt;
        const float e = __expf(-fabsf(d));
        const float A2 = (d < 0.f) ? e : 1.f;
        const float B2 = (d < 0.f) ? 1.f : e;
        p1 = A2 * p1 + B2 * vt;
        q1 = A2 * q1 + B2;
        o1 = fmaxf(w1 + o1, kt);
      }
    }
  }
  ps[j][2 * ci] = p0; qs[j][2 * ci] = q0; os[j][2 * ci] = o0;
  ps[j][2 * ci + 1] = p1; qs[j][2 * ci + 1] = q1; os[j][2 * ci + 1] = o1;
  __syncthreads();

  // ---- phase 2: Kogge-Stone inclusive scan over chunks (5 steps) ----
#pragma unroll
  for (int s = 1; s < NCH; s <<= 1) {
    float P0 = p0, Q0 = q0, O0 = o0, P1 = p1, Q1 = q1, O1 = o1;
    if (j >= s) {
      {
        const float lp = ps[j - s][2 * ci], lq = qs[j - s][2 * ci], lo = os[j - s][2 * ci];
        const float dsp = w0 * (float)(s * CL) + lo;
        const float dd = dsp - o0;
        const float e = __expf(-fabsf(dd));
        const float ea = (dd < 0.f) ? e : 1.f;
        const float eb = (dd < 0.f) ? 1.f : e;
        P0 = ea * lp + eb * p0;
        Q0 = ea * lq + eb * q0;
        O0 = fmaxf(dsp, o0);
      }
      {
        const float lp = ps[j - s][2 * ci + 1], lq = qs[j - s][2 * ci + 1], lo = os[j - s][2 * ci + 1];
        const float dsp = w1 * (float)(s * CL) + lo;
        const float dd = dsp - o1;
        const float e = __expf(-fabsf(dd));
        const float ea = (dd < 0.f) ? e : 1.f;
        const float eb = (dd < 0.f) ? 1.f : e;
        P1 = ea * lp + eb * p1;
        Q1 = ea * lq + eb * q1;
        O1 = fmaxf(dsp, o1);
      }
    }
    __syncthreads();
    p0 = P0; q0 = Q0; o0 = O0; p1 = P1; q1 = Q1; o1 = O1;
    ps[j][2 * ci] = p0; qs[j][2 * ci] = q0; os[j][2 * ci] = o0;
    ps[j][2 * ci + 1] = p1; qs[j][2 * ci + 1] = q1; os[j][2 * ci + 1] = o1;
    __syncthreads();
  }

  // ---- phase 3: re-scan with exclusive prefix, packed; emit z packed ----
  float pp0 = 0.f, qq0 = 0.f, oo0 = -1e38f;
  float pp1 = 0.f, qq1 = 0.f, oo1 = -1e38f;
  if (j > 0) {
    pp0 = ps[j - 1][2 * ci]; qq0 = qs[j - 1][2 * ci]; oo0 = os[j - 1][2 * ci];
    pp1 = ps[j - 1][2 * ci + 1]; qq1 = qs[j - 1][2 * ci + 1]; oo1 = os[j - 1][2 * ci + 1];
  }

  size_t idx = base;
#pragma unroll 4
  for (int t = 0; t < CL; ++t, idx += C_) {
    const unsigned int kk = *(const unsigned int*)(kin + idx);
    const unsigned int vv = *(const unsigned int*)(vin + idx);
    const unsigned int rr = *(const unsigned int*)(rin + idx);
    unsigned int zo;
    {
      const float kt = blo(kk), vt = blo(vv), rt = blo(rr);
      const float d1 = oo0 - (u0 + kt);
      const float e1 = __expf(-fabsf(d1));
      const float Ae = (d1 < 0.f) ? e1 : 1.f;
      const float Be = (d1 < 0.f) ? 1.f : e1;
      const float er = __expf(-rt);
      const float ysr = __fdividef(Ae * pp0 + Be * vt, (Ae * qq0 + Be) * (1.f + er));
      zo = (unsigned int)f2bf(ysr);
      const float d2 = (w0 + oo0) - kt;
      const float e2 = __expf(-fabsf(d2));
      const float A2 = (d2 < 0.f) ? e2 : 1.f;
      const float B2 = (d2 < 0.f) ? 1.f : e2;
      pp0 = A2 * pp0 + B2 * vt;
      qq0 = A2 * qq0 + B2;
      oo0 = fmaxf(w0 + oo0, kt);
    }
    {
      const float kt = bhi(kk), vt = bhi(vv), rt = bhi(rr);
      const float d1 = oo1 - (u1 + kt);
      const float e1 = __expf(-fabsf(d1));
      const float Ae = (d1 < 0.f) ? e1 : 1.f;
      const float Be = (d1 < 0.f) ? 1.f : e1;
      const float er = __expf(-rt);
      const float ysr = __fdividef(Ae * pp1 + Be * vt, (Ae * qq1 + Be) * (1.f + er));
      zo |= ((unsigned int)f2bf(ysr)) << 16;
      const float d2 = (w1 + oo1) - kt;
      const float e2 = __expf(-fabsf(d2));
      const float A2 = (d2 < 0.f) ? e2 : 1.f;
      const float B2 = (d2 < 0.f) ? 1.f : e2;
      pp1 = A2 * pp1 + B2 * vt;
      qq1 = A2 * qq1 + B2;
      oo1 = fmaxf(w1 + oo1, kt);
    }
    *(unsigned int*)(z + idx) = zo;
  }
}

// ---------------------------------------------------------------------------
extern "C" void kernel_launch(void* const* d_in, const int* in_sizes, int n_in,
                              void* d_out, int out_size, void* d_ws,
                              size_t ws_size, hipStream_t stream) {
  const float* x   = (const float*)d_in[0];
  const float* td  = (const float*)d_in[1];
  const float* tf  = (const float*)d_in[2];
  const float* tmk = (const float*)d_in[3];
  const float* tmv = (const float*)d_in[4];
  const float* tmr = (const float*)d_in[5];
  const float* Wk  = (const float*)d_in[6];
  const float* Wv  = (const float*)d_in[7];
  const float* Wr  = (const float*)d_in[8];
  const float* Wo  = (const float*)d_in[9];

  const size_t nW = (size_t)C_ * C_;
  const size_t nM = (size_t)M_ * C_;

  // ws (244.5 MiB): [wbk wbv wbr wbo][xk][xv][xr][kbuf][vbuf]  (all bf16)
  // rbuf lives in d_out (bf16; consumed by wkv before final GEMM overwrites)
  // z overlays xv (dead after gemm_v)
  unsigned short* wbk  = (unsigned short*)d_ws;
  unsigned short* wbv  = wbk + nW;
  unsigned short* wbr  = wbv + nW;
  unsigned short* wbo  = wbr + nW;
  unsigned short* xk   = wbo + nW;
  unsigned short* xv   = xk + nM;
  unsigned short* xr   = xv + nM;
  unsigned short* kbuf = xr + nM;
  unsigned short* vbuf = kbuf + nM;
  unsigned short* rbuf = (unsigned short*)d_out;
  unsigned short* zb   = xv;   // reuse

  prep<<<WBLK + MBLK, 256, 0, stream>>>(x, tmk, tmv, tmr, Wk, Wv, Wr, Wo,
                                        wbk, wbv, wbr, wbo, xk, xv, xr);

  gemm8<1><<<GNB, 512, 0, stream>>>(xk, wbk, kbuf);   // xk dies
  gemm8<1><<<GNB, 512, 0, stream>>>(xv, wbv, vbuf);   // xv dies
  gemm8<1><<<GNB, 512, 0, stream>>>(xr, wbr, rbuf);   // -> d_out (bf16)

  wkv_scan<<<B_ * (C_ / 64), 1024, 0, stream>>>(kbuf, vbuf, rbuf, td, tf, zb);

  gemm8<0><<<GNB, 512, 0, stream>>>(zb, wbo, d_out);  // f32 out
}